// Round 1
// baseline (11.228 us; speedup 1.0000x reference)
//
#include <hip/hip_runtime.h>

// Per-row gather + stable softplus + mean:
//   out = (1/N) * sum_i log(1 + exp(-input[i, label[i]]))
// Stage 1: grid-stride gather+softplus, block-reduce -> d_ws[block]
// Stage 2: one block reduces the 256 partials and scales by 1/N.
// Deterministic (no float atomics): fixed reduction tree every launch.

#define NBLK 256
#define NTHR 256

__device__ __forceinline__ float block_reduce_sum(float acc) {
    // wave64 shuffle reduce
    #pragma unroll
    for (int off = 32; off > 0; off >>= 1)
        acc += __shfl_down(acc, off, 64);
    __shared__ float s[NTHR / 64];
    const int lane = threadIdx.x & 63;
    const int wave = threadIdx.x >> 6;
    if (lane == 0) s[wave] = acc;
    __syncthreads();
    float r = 0.f;
    if (threadIdx.x == 0) {
        #pragma unroll
        for (int w = 0; w < NTHR / 64; ++w) r += s[w];
    }
    return r;
}

__global__ void softplus_gather_partial(const float* __restrict__ input,
                                        const int* __restrict__ label,
                                        float* __restrict__ partial,
                                        int N, int C) {
    const int tid    = blockIdx.x * blockDim.x + threadIdx.x;
    const int stride = gridDim.x * blockDim.x;
    float acc = 0.f;
    for (int i = tid; i < N; i += stride) {
        const int lab = label[i];                       // coalesced
        const float x = input[(long long)i * C + lab];  // 1 cacheline per row
        // softplus(-x), numerically stable
        const float z = -x;
        acc += fmaxf(z, 0.f) + log1pf(expf(-fabsf(z)));
    }
    const float b = block_reduce_sum(acc);
    if (threadIdx.x == 0) partial[blockIdx.x] = b;
}

__global__ void final_reduce(const float* __restrict__ partial,
                             float* __restrict__ out, float invN) {
    float acc = partial[threadIdx.x];  // NTHR == NBLK
    const float r = block_reduce_sum(acc);
    if (threadIdx.x == 0) out[0] = r * invN;
}

extern "C" void kernel_launch(void* const* d_in, const int* in_sizes, int n_in,
                              void* d_out, int out_size, void* d_ws, size_t ws_size,
                              hipStream_t stream) {
    const float* input = (const float*)d_in[0];
    const int*   label = (const int*)d_in[1];
    const int N = in_sizes[1];               // label count = rows
    const int C = in_sizes[0] / in_sizes[1]; // = 1000
    float* partial = (float*)d_ws;           // NBLK floats = 1 KB

    softplus_gather_partial<<<NBLK, NTHR, 0, stream>>>(input, label, partial, N, C);
    final_reduce<<<1, NTHR, 0, stream>>>(partial, (float*)d_out, 1.0f / (float)N);
}